// Round 9
// baseline (184.081 us; speedup 1.0000x reference)
//
#include <hip/hip_runtime.h>
#include <hip/hip_bf16.h>
#include <stdint.h>

typedef unsigned short u16;
typedef u16 u16x8 __attribute__((ext_vector_type(8)));
typedef u16 u16x4 __attribute__((ext_vector_type(4)));
typedef unsigned int u32x4 __attribute__((ext_vector_type(4)));
typedef __bf16 bf16x8 __attribute__((ext_vector_type(8)));
typedef float f32x4 __attribute__((ext_vector_type(4)));

#define MFMA16(a, b, c) __builtin_amdgcn_mfma_f32_16x16x32_bf16((a), (b), (c), 0, 0, 0)

#define SCALE_Q 0.18033688011112042f   /* d^-0.5 (=0.125) * log2(e) */

__device__ __forceinline__ u16 f2b(float f) {   // fp32 -> bf16 rne (4 ops)
    union { float f; unsigned u; } v; v.f = f;
    unsigned r = v.u + 0x7FFFu + ((v.u >> 16) & 1u);
    return (u16)(r >> 16);
}
__device__ __forceinline__ u16 f2b_h(float f) { // fp32 -> bf16 half-up (2 ops)
    union { float f; unsigned u; } v; v.f = f;
    return (u16)((v.u + 0x8000u) >> 16);
}
__device__ __forceinline__ unsigned pk2(float lo, float hi) {
    // 2x fp32 -> packed bf16 (RNE), 1 VALU op (T12 primitive, gfx950-verified)
    unsigned r;
    asm("v_cvt_pk_bf16_f32 %0, %1, %2" : "=v"(r) : "v"(lo), "v"(hi));
    return r;
}

__device__ __forceinline__ void gload16(const u16* g, u16* l) {
    // direct global->LDS DMA, 16 B per lane, LDS dst = wave-uniform base + lane*16
    __builtin_amdgcn_global_load_lds(
        (const __attribute__((address_space(1))) unsigned int*)g,
        (__attribute__((address_space(3))) unsigned int*)l, 16, 0, 0);
}

// ---------------------------------------------------------------------------
// Kernel 0: prep.  Blocks 0..383: W fp32->bf16 (wb[3][512 o][512 c]).
// Blocks 384..1407: x transpose+convert -> xT bf16 [16 b][1024 n][512 c]
// via a [64 c][128 n] LDS tile (coalesced reads, b128 LDS I/O, b128 stores).
// xT lives in d_out (dead before attn overwrites it).
// ---------------------------------------------------------------------------
__global__ __launch_bounds__(256) void prep(
    const float* __restrict__ x,
    const float* __restrict__ Wq, const float* __restrict__ Wk,
    const float* __restrict__ Wv,
    u16* __restrict__ wb, u16* __restrict__ xT) {
    __shared__ __align__(16) u16 Ls[128 * 72];
    const int tid = threadIdx.x;

    if (blockIdx.x < 384) {                       // ---- W convert ----
        int g = blockIdx.x * 256 + tid;           // 98304 chunks of 8
        int which = g >> 15;
        const float* src = which == 0 ? Wq : (which == 1 ? Wk : Wv);
        int off = (g & 32767) * 8;
        f32x4 a = *(const f32x4*)(src + off);
        f32x4 b = *(const f32x4*)(src + off + 4);
        u16x8 o;
#pragma unroll
        for (int i = 0; i < 4; ++i) { o[i] = f2b_h(a[i]); o[4 + i] = f2b_h(b[i]); }
        *(u16x8*)(wb + (size_t)g * 8) = o;
        return;
    }

    // ---- x transpose tile ----
    const int bid = blockIdx.x - 384;             // 0..1023
    const int b  = bid >> 6;                      // 16
    const int ct = (bid >> 3) & 7;                // 8 c-tiles of 64
    const int nt = bid & 7;                       // 8 n-tiles of 128
    const int C0 = ct * 64, N0 = nt * 128;
    const float* xb = x + ((size_t)b << 19);

#pragma unroll
    for (int rep = 0; rep < 4; ++rep) {           // stage-in: [64 c][128 n]
        int id = tid + rep * 256;
        int oct = id >> 7, n = id & 127;          // n lane-consecutive -> coalesced
        const float* xp = xb + (size_t)(C0 + oct * 8) * 1024 + N0 + n;
        u16x8 xv;
#pragma unroll
        for (int k = 0; k < 8; ++k) xv[k] = f2b_h(xp[k * 1024]);
        *(u16x8*)(Ls + n * 72 + oct * 8) = xv;    // transposed [n][c]
    }
    __syncthreads();
#pragma unroll
    for (int rep = 0; rep < 4; ++rep) {           // stage-out: rows of xT
        int id = tid + rep * 256;
        int n = id >> 3, c8 = id & 7;
        *(u16x8*)(xT + ((size_t)b << 19) + (size_t)(N0 + n) * 512 + C0 + c8 * 8) =
            *(u16x8*)(Ls + n * 72 + c8 * 8);
    }
}

// ---------------------------------------------------------------------------
// Kernel 1: QKV projection.  Same proven 128n x 128o tile, reg-staged
// single-buffer BK=64, grid 1536 — but 512 threads / 8 waves per block,
// each wave owning a 32n x 64o quadrant (wr=wave>>1 in 0..3: 32-row band;
// wc=wave&1: 64-col band).  Register ledger: acc[2][4]=32 + prefetch 16
// (xr[2],wrg[2]) + frag 24 + addr ~15 = ~90 < (512,4)'s 128 budget ->
// 2 blocks x 8 waves = 16 waves/CU (r8's (256,3) capped at 12; r7's
// acc[4][4]@512thr broke the ledger and spilled).  Aggregate staging and
// LDS traffic unchanged.  Epilogue fuses q scale, k += rel, v transpose.
//   qws: [bh][n][dd] plain;  kws: [bh][n][dd] chunk-swz by n&7;
//   vws: [bh][dd][n] PV-k-slot-permuted + chunk-swz by dd&7.
// ---------------------------------------------------------------------------
__global__ __launch_bounds__(512, 4) void qkv_proj(
    const u16* __restrict__ xT, const u16* __restrict__ wb,
    const float* __restrict__ bq, const float* __restrict__ bk,
    const float* __restrict__ bv,
    const float* __restrict__ rel_h, const float* __restrict__ rel_w,
    u16* __restrict__ qws, u16* __restrict__ kws, u16* __restrict__ vws) {
    __shared__ __align__(16) u16 Xs[128 * 72];   // [128 n][72]
    __shared__ __align__(16) u16 Ws[128 * 72];   // [128 o][72]

    const int tid  = threadIdx.x;
    const int wave = tid >> 6, lane = tid & 63;
    const int quad = lane >> 4, l16 = lane & 15;
    const int wr = wave >> 1, wc = wave & 1;     // 4 n-bands x 2 o-bands

    const int id = blockIdx.x;           // 1536 = 8 nt * (4 o0 * 3 mm * 16 b)
    const int nt = id & 7;               // XCD selector
    const int r  = id >> 3;
    const int o0 = r & 3;
    const int r2 = r >> 2;
    const int mm = r2 % 3;
    const int b  = r2 / 3;
    const int N0 = nt * 128;
    const int O0 = o0 * 128;

    const u16*   W    = wb + (size_t)mm * 262144;    // [512 o][512 c]
    const float* bias = mm == 0 ? bq : (mm == 1 ? bk : bv);
    const u16*   Xb   = xT + ((size_t)b << 19);      // [1024 n][512 c]

    const int sr = tid >> 3, sc8 = tid & 7;          // staging row (0..63)/octet

    u16x8 xr[2], wrg[2];
#pragma unroll
    for (int rp = 0; rp < 2; ++rp) {                 // prefetch kt=0
        xr[rp]  = *(const u16x8*)(Xb + (size_t)(N0 + sr + rp * 64) * 512 + sc8 * 8);
        wrg[rp] = *(const u16x8*)(W  + (size_t)(O0 + sr + rp * 64) * 512 + sc8 * 8);
    }

    f32x4 acc[2][4] = {};

    for (int kt = 0; kt < 8; ++kt) {     // K = 512, BK = 64
        __syncthreads();                 // prior frag reads done
#pragma unroll
        for (int rp = 0; rp < 2; ++rp) {
            *(u16x8*)(Xs + (sr + rp * 64) * 72 + sc8 * 8) = xr[rp];
            *(u16x8*)(Ws + (sr + rp * 64) * 72 + sc8 * 8) = wrg[rp];
        }
        __syncthreads();
        if (kt < 7) {
            int c0 = (kt + 1) * 64;
#pragma unroll
            for (int rp = 0; rp < 2; ++rp) {
                xr[rp]  = *(const u16x8*)(Xb + (size_t)(N0 + sr + rp * 64) * 512 + c0 + sc8 * 8);
                wrg[rp] = *(const u16x8*)(W  + (size_t)(O0 + sr + rp * 64) * 512 + c0 + sc8 * 8);
            }
        }
#pragma unroll
        for (int kk = 0; kk < 2; ++kk) {
            bf16x8 af[2], bfr[4];
#pragma unroll
            for (int mi = 0; mi < 2; ++mi)
                af[mi] = *(bf16x8*)(Xs + (wr * 32 + mi * 16 + l16) * 72 + kk * 32 + quad * 8);
#pragma unroll
            for (int ni = 0; ni < 4; ++ni)
                bfr[ni] = *(bf16x8*)(Ws + (wc * 64 + ni * 16 + l16) * 72 + kk * 32 + quad * 8);
#pragma unroll
            for (int mi = 0; mi < 2; ++mi)
#pragma unroll
                for (int ni = 0; ni < 4; ++ni)
                    acc[mi][ni] = MFMA16(af[mi], bfr[ni], acc[mi][ni]);
        }
    }

    // Epilogue. C-layout: col (o-dim) = l16, row (n-dim) = quad*4 + r.
#pragma unroll
    for (int mi = 0; mi < 2; ++mi) {
#pragma unroll
        for (int ni = 0; ni < 4; ++ni) {
            int o  = O0 + wc * 64 + ni * 16 + l16;
            int h  = o >> 6, dd = o & 63;
            size_t bh = (size_t)b * 8 + h;
            float bv_ = bias[o];
            int n0 = N0 + wr * 32 + mi * 16 + quad * 4;
            if (mm == 2) {
                u16x4 pk;
#pragma unroll
                for (int rr = 0; rr < 4; ++rr) pk[rr] = f2b(acc[mi][ni][rr] + bv_);
                // V column permutation (PV k-slot alignment): n=..|16s+4q+r
                // -> phys ..|8q+4s+r, then chunk swizzle by dd&7.
                int qq = (n0 >> 2) & 3, ss = (n0 >> 4) & 1;
                int np = (n0 & ~31) | (qq * 8 + ss * 4);
                int slot = ((np >> 3) & 7) ^ (dd & 7);
                int np2 = (np & ~63) | (slot << 3) | (np & 7);
                *(u16x4*)(vws + (bh * 64 + dd) * 1024 + np2) = pk;
            } else if (mm == 0) {
#pragma unroll
                for (int rr = 0; rr < 4; ++rr)
                    qws[(bh * 1024 + (n0 + rr)) * 64 + dd] =
                        f2b((acc[mi][ni][rr] + bv_) * SCALE_Q);
            } else {
                float th = rel_h[dd * 32 + (n0 >> 5)];
                f32x4 tw = *(const f32x4*)(rel_w + dd * 32 + (n0 & 31));
#pragma unroll
                for (int rr = 0; rr < 4; ++rr) {
                    int n = n0 + rr;
                    int sdd = (((dd >> 3) ^ (n & 7)) << 3) | (dd & 7);
                    kws[(bh * 1024 + n) * 64 + sdd] =
                        f2b(acc[mi][ni][rr] + bv_ + th + tw[rr]);
                }
            }
        }
    }
}

// ---------------------------------------------------------------------------
// Kernel 2: flash attention, 512 threads / 8 waves, 32 q-rows per wave
// (256 q-rows per block -> grid 512 = 2 blocks/CU).  K/V staged by
// global_load_lds into double-buffered [64][64] tiles; chunk XOR-swizzle
// baked into kws/vws (SQ_LDS_BANK_CONFLICT=0 verified).  P stays in
// registers (swapped QK^T + vws k-slot permutation); P->bf16 packing via
// v_cvt_pk_bf16_f32.  UNCHANGED from round 6/8.
// ---------------------------------------------------------------------------
__global__ __launch_bounds__(512, 4) void attn(
    const u16* __restrict__ qws, const u16* __restrict__ kws,
    const u16* __restrict__ vws, float* __restrict__ out) {
    __shared__ __align__(16) u16 KPb[2][64 * 64];   // K tiles [64 j][64 dd]
    __shared__ __align__(16) u16 Vtb[2][64 * 64];   // V^T tiles [64 dd][64 j]

    const int tid  = threadIdx.x;
    const int wave = tid >> 6, lane = tid & 63;
    const int quad = lane >> 4, l16 = lane & 15;
    const int id = blockIdx.x;        // 512 = (b*4 + qt)*8 + h
    const int h  = id & 7;            // XCD selector
    const int qt = (id >> 3) & 3;
    const int b  = id >> 5;
    const size_t bh = (size_t)b * 8 + h;

    const u16* Q = qws + (bh * 1024 + (size_t)qt * 256) * 64;
    const u16* K = kws + bh * 65536;
    const u16* V = vws + bh * 65536;

    // per-lane global source for DMA staging: wave w feeds tile rows 8w..8w+7
    const int lrow = wave * 8 + (lane >> 3);
    const int lc8  = lane & 7;
    const u16* Kl = K + (size_t)lrow * 64 + lc8 * 8;
    const u16* Vl = V + ((size_t)lrow << 10) + lc8 * 8;
    u16* const KP0 = &KPb[0][0];
    u16* const Vt0 = &Vtb[0][0];
    const int wofs = wave * 512;      // wave-uniform LDS dst offset (u16)

    bf16x8 qf[2][2];
#pragma unroll
    for (int ni = 0; ni < 2; ++ni)
#pragma unroll
        for (int ks = 0; ks < 2; ++ks)
            qf[ni][ks] = *(const bf16x8*)(Q + (wave * 32 + ni * 16 + l16) * 64 + ks * 32 + quad * 8);

    // inverse-XOR in-row byte offsets for fragment reads
    const int xsw = (l16 & 7) << 4;
    const int xk0 = (quad * 16) ^ xsw;
    const int xk1 = (64 + quad * 16) ^ xsw;

    f32x4 accO[4][2] = {};
    f32x4 s4[2] = {};

    gload16(Kl, KP0 + wofs);          // stage jt=0 into buf 0
    gload16(Vl, Vt0 + wofs);

    auto body = [&](int jt, int cur) {
        __syncthreads();              // vmcnt(0)+barrier: buf[cur] staged
        if (jt < 15) {                // prefetch jt+1 into the other buffer
            int nxt = cur ^ 1;
            gload16(Kl + (jt + 1) * 4096, KP0 + nxt * 4096 + wofs);
            gload16(Vl + (jt + 1) * 64,  Vt0 + nxt * 4096 + wofs);
        }
        const char* KP = (const char*)(KP0 + cur * 4096);
        const char* Vt = (const char*)(Vt0 + cur * 4096);

        // ---- QK^T (swapped: A=K rows j, B=Q cols i) ----
        f32x4 aST[4][2] = {};
#pragma unroll
        for (int ks = 0; ks < 2; ++ks) {
            const int xo = ks ? xk1 : xk0;
            bf16x8 kf[4];
#pragma unroll
            for (int mj = 0; mj < 4; ++mj)
                kf[mj] = *(const bf16x8*)(KP + (mj * 16 + l16) * 128 + xo);
            __builtin_amdgcn_s_setprio(1);
#pragma unroll
            for (int mj = 0; mj < 4; ++mj)
#pragma unroll
                for (int ni = 0; ni < 2; ++ni)
                    aST[mj][ni] = MFMA16(kf[mj], qf[ni][ks], aST[mj][ni]);
            __builtin_amdgcn_s_setprio(0);
        }

        // ---- softmax: p = exp2(s); per-lane partial row-sums ----
#pragma unroll
        for (int mj = 0; mj < 4; ++mj)
#pragma unroll
            for (int ni = 0; ni < 2; ++ni) {
                f32x4 p;
#pragma unroll
                for (int rr = 0; rr < 4; ++rr)
                    p[rr] = __builtin_amdgcn_exp2f(aST[mj][ni][rr]);
                s4[ni] += p;
                aST[mj][ni] = p;
            }

        // ---- PV: pack P to bf16 in regs (cvt_pk), per k-slice ----
#pragma unroll
        for (int ks2 = 0; ks2 < 2; ++ks2) {
            union { u32x4 u; bf16x8 b; } pfr[2];
#pragma unroll
            for (int ni = 0; ni < 2; ++ni) {
                pfr[ni].u[0] = pk2(aST[2 * ks2][ni][0],     aST[2 * ks2][ni][1]);
                pfr[ni].u[1] = pk2(aST[2 * ks2][ni][2],     aST[2 * ks2][ni][3]);
                pfr[ni].u[2] = pk2(aST[2 * ks2 + 1][ni][0], aST[2 * ks2 + 1][ni][1]);
                pfr[ni].u[3] = pk2(aST[2 * ks2 + 1][ni][2], aST[2 * ks2 + 1][ni][3]);
            }
            const int xo = ks2 ? xk1 : xk0;
            bf16x8 vf[4];
#pragma unroll
            for (int md = 0; md < 4; ++md)
                vf[md] = *(const bf16x8*)(Vt + (md * 16 + l16) * 128 + xo);
            __builtin_amdgcn_s_setprio(1);
#pragma unroll
            for (int md = 0; md < 4; ++md)
#pragma unroll
                for (int ni = 0; ni < 2; ++ni)
                    accO[md][ni] = MFMA16(vf[md], pfr[ni].b, accO[md][ni]);
            __builtin_amdgcn_s_setprio(0);
        }
    };

    for (int j2 = 0; j2 < 8; ++j2) {  // unroll-by-2: compile-time buffer sel
        body(2 * j2,     0);
        body(2 * j2 + 1, 1);
    }

#pragma unroll
    for (int ni = 0; ni < 2; ++ni) {
        float rs = (s4[ni][0] + s4[ni][1]) + (s4[ni][2] + s4[ni][3]);
        rs += __shfl_xor(rs, 16);
        rs += __shfl_xor(rs, 32);
        float inv = 1.0f / rs;
        int i = qt * 256 + wave * 32 + ni * 16 + l16;
#pragma unroll
        for (int md = 0; md < 4; ++md) {
            f32x4 pk;
#pragma unroll
            for (int rr = 0; rr < 4; ++rr) pk[rr] = accO[md][ni][rr] * inv;
            *(f32x4*)(out + (bh * 1024 + i) * 64 + md * 16 + quad * 4) = pk;
        }
    }
}

// ---------------------------------------------------------------------------
extern "C" void kernel_launch(void* const* d_in, const int* in_sizes, int n_in,
                              void* d_out, int out_size, void* d_ws, size_t ws_size,
                              hipStream_t stream) {
    const float* x  = (const float*)d_in[0];
    const float* Wq = (const float*)d_in[1];
    const float* bq = (const float*)d_in[2];
    const float* Wk = (const float*)d_in[3];
    const float* bk = (const float*)d_in[4];
    const float* Wv = (const float*)d_in[5];
    const float* bv = (const float*)d_in[6];
    const float* rh = (const float*)d_in[7];
    const float* rw = (const float*)d_in[8];
    float* out = (float*)d_out;

    u16* kws = (u16*)d_ws;            // 16 MB bf16 [bh][n][dd-swz]
    u16* vws = kws + 8388608;         // 16 MB bf16 [bh][dd][n-perm-swz]
    u16* qws = vws + 8388608;         // 16 MB bf16 [bh][n][dd]
    u16* wb  = qws + 8388608;         // 1.5 MB bf16 [3][512][512] (ws: 49.5 MB)
    u16* xT  = (u16*)d_out;           // 16.8 MB bf16 [16][1024][512] in d_out
                                      // (dead before attn overwrites d_out)

    prep<<<1408, 256, 0, stream>>>(x, Wq, Wk, Wv, wb, xT);
    qkv_proj<<<1536, 512, 0, stream>>>(xT, wb, bq, bk, bv, rh, rw, qws, kws, vws);
    attn<<<512, 512, 0, stream>>>(qws, kws, vws, out);
}

// Round 11
// 178.957 us; speedup vs baseline: 1.0286x; 1.0286x over previous
//
#include <hip/hip_runtime.h>
#include <hip/hip_bf16.h>
#include <stdint.h>

typedef unsigned short u16;
typedef u16 u16x8 __attribute__((ext_vector_type(8)));
typedef u16 u16x4 __attribute__((ext_vector_type(4)));
typedef unsigned int u32x4 __attribute__((ext_vector_type(4)));
typedef __bf16 bf16x8 __attribute__((ext_vector_type(8)));
typedef float f32x4 __attribute__((ext_vector_type(4)));

#define MFMA16(a, b, c) __builtin_amdgcn_mfma_f32_16x16x32_bf16((a), (b), (c), 0, 0, 0)

#define SCALE_Q 0.18033688011112042f   /* d^-0.5 (=0.125) * log2(e) */

__device__ __forceinline__ u16 f2b(float f) {   // fp32 -> bf16 rne (4 ops)
    union { float f; unsigned u; } v; v.f = f;
    unsigned r = v.u + 0x7FFFu + ((v.u >> 16) & 1u);
    return (u16)(r >> 16);
}
__device__ __forceinline__ u16 f2b_h(float f) { // fp32 -> bf16 half-up (2 ops)
    union { float f; unsigned u; } v; v.f = f;
    return (u16)((v.u + 0x8000u) >> 16);
}
__device__ __forceinline__ unsigned pk2(float lo, float hi) {
    // 2x fp32 -> packed bf16 (RNE), 1 VALU op (T12 primitive, gfx950-verified)
    unsigned r;
    asm("v_cvt_pk_bf16_f32 %0, %1, %2" : "=v"(r) : "v"(lo), "v"(hi));
    return r;
}

__device__ __forceinline__ void gload16(const u16* g, u16* l) {
    // direct global->LDS DMA, 16 B per lane, LDS dst = wave-uniform base + lane*16
    __builtin_amdgcn_global_load_lds(
        (const __attribute__((address_space(1))) unsigned int*)g,
        (__attribute__((address_space(3))) unsigned int*)l, 16, 0, 0);
}

// ---------------------------------------------------------------------------
// Kernel 0: prep.  Blocks 0..383: W fp32->bf16 (wb[3][512 o][512 c]).
// Blocks 384..1407: x transpose+convert -> xT bf16 [16 b][1024 n][512 c]
// via a [64 c][128 n] LDS tile (coalesced reads, b128 LDS I/O, b128 stores).
// xT lives in d_out (dead before attn overwrites it).
// ---------------------------------------------------------------------------
__global__ __launch_bounds__(256) void prep(
    const float* __restrict__ x,
    const float* __restrict__ Wq, const float* __restrict__ Wk,
    const float* __restrict__ Wv,
    u16* __restrict__ wb, u16* __restrict__ xT) {
    __shared__ __align__(16) u16 Ls[128 * 72];
    const int tid = threadIdx.x;

    if (blockIdx.x < 384) {                       // ---- W convert ----
        int g = blockIdx.x * 256 + tid;           // 98304 chunks of 8
        int which = g >> 15;
        const float* src = which == 0 ? Wq : (which == 1 ? Wk : Wv);
        int off = (g & 32767) * 8;
        f32x4 a = *(const f32x4*)(src + off);
        f32x4 b = *(const f32x4*)(src + off + 4);
        u16x8 o;
#pragma unroll
        for (int i = 0; i < 4; ++i) { o[i] = f2b_h(a[i]); o[4 + i] = f2b_h(b[i]); }
        *(u16x8*)(wb + (size_t)g * 8) = o;
        return;
    }

    // ---- x transpose tile ----
    const int bid = blockIdx.x - 384;             // 0..1023
    const int b  = bid >> 6;                      // 16
    const int ct = (bid >> 3) & 7;                // 8 c-tiles of 64
    const int nt = bid & 7;                       // 8 n-tiles of 128
    const int C0 = ct * 64, N0 = nt * 128;
    const float* xb = x + ((size_t)b << 19);

#pragma unroll
    for (int rep = 0; rep < 4; ++rep) {           // stage-in: [64 c][128 n]
        int id = tid + rep * 256;
        int oct = id >> 7, n = id & 127;          // n lane-consecutive -> coalesced
        const float* xp = xb + (size_t)(C0 + oct * 8) * 1024 + N0 + n;
        u16x8 xv;
#pragma unroll
        for (int k = 0; k < 8; ++k) xv[k] = f2b_h(xp[k * 1024]);
        *(u16x8*)(Ls + n * 72 + oct * 8) = xv;    // transposed [n][c]
    }
    __syncthreads();
#pragma unroll
    for (int rep = 0; rep < 4; ++rep) {           // stage-out: rows of xT
        int id = tid + rep * 256;
        int n = id >> 3, c8 = id & 7;
        *(u16x8*)(xT + ((size_t)b << 19) + (size_t)(N0 + n) * 512 + C0 + c8 * 8) =
            *(u16x8*)(Ls + n * 72 + c8 * 8);
    }
}

// ---------------------------------------------------------------------------
// Kernel 1: QKV projection — DMA-staged with the attn-proven machinery.
// 512 threads / 8 waves, 128n x 128o tile, each wave a 32n x 64o quadrant.
// K-loop: BK=64, double-buffered unpadded [128][64] bf16 tiles staged by
// global_load_lds (4 calls/thread/kt), ONE barrier per kt.  At each barrier
// a wave drains only ITS DMAs, issued one full 32-MFMA compute phase
// earlier (~450 cyc >= L2 latency; X tile L2-shared by 12 blocks, W by
// 128).  Bank-conflict-free reads via the source-chunk XOR involution:
// lane l sources chunk (l&7)^((l>>3)&7) so LDS slot s of row r holds
// chunk s^(r&7); frag reads use slot (kk*4+quad)^(l16&7)  (attn-verified).
// vs r9: 8 fewer barriers, zero staging ds_writes/VALU, -16 prefetch VGPRs
// (ledger ~76 << 128).  r6's DMA failure was BK=32's short window, fixed.
// Epilogue (unchanged): q scale, k += rel table, v transpose.
//   qws: [bh][n][dd] plain;  kws: [bh][n][dd] chunk-swz by n&7;
//   vws: [bh][dd][n] PV-k-slot-permuted + chunk-swz by dd&7.
// ---------------------------------------------------------------------------
__global__ __launch_bounds__(512, 4) void qkv_proj(
    const u16* __restrict__ xT, const u16* __restrict__ wb,
    const float* __restrict__ bq, const float* __restrict__ bk,
    const float* __restrict__ bv,
    const float* __restrict__ rel_h, const float* __restrict__ rel_w,
    u16* __restrict__ qws, u16* __restrict__ kws, u16* __restrict__ vws) {
    __shared__ __align__(16) u16 Xs2[2][128 * 64];   // 32 KB
    __shared__ __align__(16) u16 Ws2[2][128 * 64];   // 32 KB

    const int tid  = threadIdx.x;
    const int wave = tid >> 6, lane = tid & 63;
    const int quad = lane >> 4, l16 = lane & 15;
    const int wr = wave >> 1, wc = wave & 1;     // 4 n-bands x 2 o-bands

    const int id = blockIdx.x;           // 1536 = 8 nt * (4 o0 * 3 mm * 16 b)
    const int nt = id & 7;               // XCD selector
    const int r  = id >> 3;
    const int o0 = r & 3;
    const int r2 = r >> 2;
    const int mm = r2 % 3;
    const int b  = r2 / 3;
    const int N0 = nt * 128;
    const int O0 = o0 * 128;

    const u16*   W    = wb + (size_t)mm * 262144;    // [512 o][512 c]
    const float* bias = mm == 0 ? bq : (mm == 1 ? bk : bv);
    const u16*   Xb   = xT + ((size_t)b << 19);      // [1024 n][512 c]

    // DMA source: wave w, lane l -> tile row w*8+(l>>3) (+64 on call 2),
    // source chunk = (l&7)^((l>>3)&7)  (rows are multiples of 8 per wave,
    // so row&7 == (l>>3)&7 for both calls).
    const int srow   = wave * 8 + (lane >> 3);
    const int schunk = (lane & 7) ^ ((lane >> 3) & 7);
    const u16* Xg0 = Xb + (size_t)(N0 + srow) * 512      + schunk * 8;
    const u16* Xg1 = Xb + (size_t)(N0 + 64 + srow) * 512 + schunk * 8;
    const u16* Wg0 = W  + (size_t)(O0 + srow) * 512      + schunk * 8;
    const u16* Wg1 = W  + (size_t)(O0 + 64 + srow) * 512 + schunk * 8;
    u16* const XL = &Xs2[0][0];
    u16* const WL = &Ws2[0][0];
    const int wofs = wave * 512;         // wave-uniform LDS dst (u16)

    auto STAGE = [&](int kt, int buf) {
        int c0 = kt * 64;
        gload16(Xg0 + c0, XL + buf * 8192 + wofs);
        gload16(Xg1 + c0, XL + buf * 8192 + 4096 + wofs);
        gload16(Wg0 + c0, WL + buf * 8192 + wofs);
        gload16(Wg1 + c0, WL + buf * 8192 + 4096 + wofs);
    };

    f32x4 acc[2][4] = {};
    const int sl0 = (l16 & 7) * 8;       // read-slot XOR base (u16 units)

    STAGE(0, 0);

    auto step = [&](int kt, int cur) {
        __syncthreads();                 // own-vmcnt drain: buf[cur] staged;
                                         // also orders reads(kt-1) vs DMAs(kt+1)
        if (kt < 7) STAGE(kt + 1, cur ^ 1);
        const u16* Xc = XL + cur * 8192;
        const u16* Wc = WL + cur * 8192;
#pragma unroll
        for (int kk = 0; kk < 2; ++kk) {
            const int so = (((kk * 4 + quad) * 8) ^ sl0);   // slot*8 u16
            bf16x8 af[2], bfr[4];
#pragma unroll
            for (int mi = 0; mi < 2; ++mi)
                af[mi] = *(const bf16x8*)(Xc + (wr * 32 + mi * 16 + l16) * 64 + so);
#pragma unroll
            for (int ni = 0; ni < 4; ++ni)
                bfr[ni] = *(const bf16x8*)(Wc + (wc * 64 + ni * 16 + l16) * 64 + so);
            __builtin_amdgcn_s_setprio(1);
#pragma unroll
            for (int mi = 0; mi < 2; ++mi)
#pragma unroll
                for (int ni = 0; ni < 4; ++ni)
                    acc[mi][ni] = MFMA16(af[mi], bfr[ni], acc[mi][ni]);
            __builtin_amdgcn_s_setprio(0);
        }
    };

    for (int k2 = 0; k2 < 4; ++k2) {     // K = 512, BK = 64, dbuf
        step(2 * k2,     0);
        step(2 * k2 + 1, 1);
    }

    // Epilogue. C-layout: col (o-dim) = l16, row (n-dim) = quad*4 + r.
#pragma unroll
    for (int mi = 0; mi < 2; ++mi) {
#pragma unroll
        for (int ni = 0; ni < 4; ++ni) {
            int o  = O0 + wc * 64 + ni * 16 + l16;
            int h  = o >> 6, dd = o & 63;
            size_t bh = (size_t)b * 8 + h;
            float bv_ = bias[o];
            int n0 = N0 + wr * 32 + mi * 16 + quad * 4;
            if (mm == 2) {
                u16x4 pk;
#pragma unroll
                for (int rr = 0; rr < 4; ++rr) pk[rr] = f2b(acc[mi][ni][rr] + bv_);
                // V column permutation (PV k-slot alignment): n=..|16s+4q+r
                // -> phys ..|8q+4s+r, then chunk swizzle by dd&7.
                int qq = (n0 >> 2) & 3, ss = (n0 >> 4) & 1;
                int np = (n0 & ~31) | (qq * 8 + ss * 4);
                int slot = ((np >> 3) & 7) ^ (dd & 7);
                int np2 = (np & ~63) | (slot << 3) | (np & 7);
                *(u16x4*)(vws + (bh * 64 + dd) * 1024 + np2) = pk;
            } else if (mm == 0) {
#pragma unroll
                for (int rr = 0; rr < 4; ++rr)
                    qws[(bh * 1024 + (n0 + rr)) * 64 + dd] =
                        f2b((acc[mi][ni][rr] + bv_) * SCALE_Q);
            } else {
                float th = rel_h[dd * 32 + (n0 >> 5)];
                f32x4 tw = *(const f32x4*)(rel_w + dd * 32 + (n0 & 31));
#pragma unroll
                for (int rr = 0; rr < 4; ++rr) {
                    int n = n0 + rr;
                    int sdd = (((dd >> 3) ^ (n & 7)) << 3) | (dd & 7);
                    kws[(bh * 1024 + n) * 64 + sdd] =
                        f2b(acc[mi][ni][rr] + bv_ + th + tw[rr]);
                }
            }
        }
    }
}

// ---------------------------------------------------------------------------
// Kernel 2: flash attention, 512 threads / 8 waves, 32 q-rows per wave
// (256 q-rows per block -> grid 512 = 2 blocks/CU).  K/V staged by
// global_load_lds into double-buffered [64][64] tiles; chunk XOR-swizzle
// baked into kws/vws (SQ_LDS_BANK_CONFLICT=0 verified).  P stays in
// registers (swapped QK^T + vws k-slot permutation); P->bf16 packing via
// v_cvt_pk_bf16_f32.  UNCHANGED from round 6/8/9.
// ---------------------------------------------------------------------------
__global__ __launch_bounds__(512, 4) void attn(
    const u16* __restrict__ qws, const u16* __restrict__ kws,
    const u16* __restrict__ vws, float* __restrict__ out) {
    __shared__ __align__(16) u16 KPb[2][64 * 64];   // K tiles [64 j][64 dd]
    __shared__ __align__(16) u16 Vtb[2][64 * 64];   // V^T tiles [64 dd][64 j]

    const int tid  = threadIdx.x;
    const int wave = tid >> 6, lane = tid & 63;
    const int quad = lane >> 4, l16 = lane & 15;
    const int id = blockIdx.x;        // 512 = (b*4 + qt)*8 + h
    const int h  = id & 7;            // XCD selector
    const int qt = (id >> 3) & 3;
    const int b  = id >> 5;
    const size_t bh = (size_t)b * 8 + h;

    const u16* Q = qws + (bh * 1024 + (size_t)qt * 256) * 64;
    const u16* K = kws + bh * 65536;
    const u16* V = vws + bh * 65536;

    // per-lane global source for DMA staging: wave w feeds tile rows 8w..8w+7
    const int lrow = wave * 8 + (lane >> 3);
    const int lc8  = lane & 7;
    const u16* Kl = K + (size_t)lrow * 64 + lc8 * 8;
    const u16* Vl = V + ((size_t)lrow << 10) + lc8 * 8;
    u16* const KP0 = &KPb[0][0];
    u16* const Vt0 = &Vtb[0][0];
    const int wofs = wave * 512;      // wave-uniform LDS dst offset (u16)

    bf16x8 qf[2][2];
#pragma unroll
    for (int ni = 0; ni < 2; ++ni)
#pragma unroll
        for (int ks = 0; ks < 2; ++ks)
            qf[ni][ks] = *(const bf16x8*)(Q + (wave * 32 + ni * 16 + l16) * 64 + ks * 32 + quad * 8);

    // inverse-XOR in-row byte offsets for fragment reads
    const int xsw = (l16 & 7) << 4;
    const int xk0 = (quad * 16) ^ xsw;
    const int xk1 = (64 + quad * 16) ^ xsw;

    f32x4 accO[4][2] = {};
    f32x4 s4[2] = {};

    gload16(Kl, KP0 + wofs);          // stage jt=0 into buf 0
    gload16(Vl, Vt0 + wofs);

    auto body = [&](int jt, int cur) {
        __syncthreads();              // vmcnt(0)+barrier: buf[cur] staged
        if (jt < 15) {                // prefetch jt+1 into the other buffer
            int nxt = cur ^ 1;
            gload16(Kl + (jt + 1) * 4096, KP0 + nxt * 4096 + wofs);
            gload16(Vl + (jt + 1) * 64,  Vt0 + nxt * 4096 + wofs);
        }
        const char* KP = (const char*)(KP0 + cur * 4096);
        const char* Vt = (const char*)(Vt0 + cur * 4096);

        // ---- QK^T (swapped: A=K rows j, B=Q cols i) ----
        f32x4 aST[4][2] = {};
#pragma unroll
        for (int ks = 0; ks < 2; ++ks) {
            const int xo = ks ? xk1 : xk0;
            bf16x8 kf[4];
#pragma unroll
            for (int mj = 0; mj < 4; ++mj)
                kf[mj] = *(const bf16x8*)(KP + (mj * 16 + l16) * 128 + xo);
            __builtin_amdgcn_s_setprio(1);
#pragma unroll
            for (int mj = 0; mj < 4; ++mj)
#pragma unroll
                for (int ni = 0; ni < 2; ++ni)
                    aST[mj][ni] = MFMA16(kf[mj], qf[ni][ks], aST[mj][ni]);
            __builtin_amdgcn_s_setprio(0);
        }

        // ---- softmax: p = exp2(s); per-lane partial row-sums ----
#pragma unroll
        for (int mj = 0; mj < 4; ++mj)
#pragma unroll
            for (int ni = 0; ni < 2; ++ni) {
                f32x4 p;
#pragma unroll
                for (int rr = 0; rr < 4; ++rr)
                    p[rr] = __builtin_amdgcn_exp2f(aST[mj][ni][rr]);
                s4[ni] += p;
                aST[mj][ni] = p;
            }

        // ---- PV: pack P to bf16 in regs (cvt_pk), per k-slice ----
#pragma unroll
        for (int ks2 = 0; ks2 < 2; ++ks2) {
            union { u32x4 u; bf16x8 b; } pfr[2];
#pragma unroll
            for (int ni = 0; ni < 2; ++ni) {
                pfr[ni].u[0] = pk2(aST[2 * ks2][ni][0],     aST[2 * ks2][ni][1]);
                pfr[ni].u[1] = pk2(aST[2 * ks2][ni][2],     aST[2 * ks2][ni][3]);
                pfr[ni].u[2] = pk2(aST[2 * ks2 + 1][ni][0], aST[2 * ks2 + 1][ni][1]);
                pfr[ni].u[3] = pk2(aST[2 * ks2 + 1][ni][2], aST[2 * ks2 + 1][ni][3]);
            }
            const int xo = ks2 ? xk1 : xk0;
            bf16x8 vf[4];
#pragma unroll
            for (int md = 0; md < 4; ++md)
                vf[md] = *(const bf16x8*)(Vt + (md * 16 + l16) * 128 + xo);
            __builtin_amdgcn_s_setprio(1);
#pragma unroll
            for (int md = 0; md < 4; ++md)
#pragma unroll
                for (int ni = 0; ni < 2; ++ni)
                    accO[md][ni] = MFMA16(vf[md], pfr[ni].b, accO[md][ni]);
            __builtin_amdgcn_s_setprio(0);
        }
    };

    for (int j2 = 0; j2 < 8; ++j2) {  // unroll-by-2: compile-time buffer sel
        body(2 * j2,     0);
        body(2 * j2 + 1, 1);
    }

#pragma unroll
    for (int ni = 0; ni < 2; ++ni) {
        float rs = (s4[ni][0] + s4[ni][1]) + (s4[ni][2] + s4[ni][3]);
        rs += __shfl_xor(rs, 16);
        rs += __shfl_xor(rs, 32);
        float inv = 1.0f / rs;
        int i = qt * 256 + wave * 32 + ni * 16 + l16;
#pragma unroll
        for (int md = 0; md < 4; ++md) {
            f32x4 pk;
#pragma unroll
            for (int rr = 0; rr < 4; ++rr) pk[rr] = accO[md][ni][rr] * inv;
            *(f32x4*)(out + (bh * 1024 + i) * 64 + md * 16 + quad * 4) = pk;
        }
    }
}

// ---------------------------------------------------------------------------
extern "C" void kernel_launch(void* const* d_in, const int* in_sizes, int n_in,
                              void* d_out, int out_size, void* d_ws, size_t ws_size,
                              hipStream_t stream) {
    const float* x  = (const float*)d_in[0];
    const float* Wq = (const float*)d_in[1];
    const float* bq = (const float*)d_in[2];
    const float* Wk = (const float*)d_in[3];
    const float* bk = (const float*)d_in[4];
    const float* Wv = (const float*)d_in[5];
    const float* bv = (const float*)d_in[6];
    const float* rh = (const float*)d_in[7];
    const float* rw = (const float*)d_in[8];
    float* out = (float*)d_out;

    u16* kws = (u16*)d_ws;            // 16 MB bf16 [bh][n][dd-swz]
    u16* vws = kws + 8388608;         // 16 MB bf16 [bh][dd][n-perm-swz]
    u16* qws = vws + 8388608;         // 16 MB bf16 [bh][n][dd]
    u16* wb  = qws + 8388608;         // 1.5 MB bf16 [3][512][512] (ws: 49.5 MB)
    u16* xT  = (u16*)d_out;           // 16.8 MB bf16 [16][1024][512] in d_out
                                      // (dead before attn overwrites d_out)

    prep<<<1408, 256, 0, stream>>>(x, Wq, Wk, Wv, wb, xT);
    qkv_proj<<<1536, 512, 0, stream>>>(xT, wb, bq, bk, bv, rh, rw, qws, kws, vws);
    attn<<<512, 512, 0, stream>>>(qws, kws, vws, out);
}